// Round 11
// baseline (234.028 us; speedup 1.0000x reference)
//
#include <hip/hip_runtime.h>
#include <hip/hip_bf16.h>

#define N 8192
#define FIN 256
#define FOUT 128
#define ALPHA 0.2f

typedef unsigned short ushort_t;
typedef __attribute__((ext_vector_type(8))) short short8;
typedef __attribute__((ext_vector_type(4))) float f32x4;

#define GLOAD16(gp, lp)                                        \
  __builtin_amdgcn_global_load_lds(                            \
      (const __attribute__((address_space(1))) void*)(gp),     \
      (__attribute__((address_space(3))) void*)(lp), 16, 0, 0)

__device__ __forceinline__ ushort_t f2bf(float x) {
  __hip_bfloat16 b = __float2bfloat16(x);  // RNE
  return *reinterpret_cast<ushort_t*>(&b);
}

// ---------------- Kernel 0: contiguous grid-stride pack of adj>0 ------------------
// Proven ~5.6 TB/s shape (r5): whole GPU sweeps adj contiguously, one uint32 word
// (32 adj ints = 128 B) per thread per iter. Separate from k_h (r10 post-mortem:
// fusing them SLOWS the stream).
__global__ __launch_bounds__(256) void k_pack(const int* __restrict__ adj,
                                              unsigned* __restrict__ maskRM) {
  const size_t tid = (size_t)blockIdx.x * 256 + threadIdx.x;
  const size_t nthr = (size_t)gridDim.x * 256;
  const size_t nwords = (size_t)N * (N / 32);
  for (size_t w = tid; w < nwords; w += nthr) {
    const int4* p = reinterpret_cast<const int4*>(adj + w * 32);
    unsigned m = 0;
#pragma unroll
    for (int s = 0; s < 8; ++s) {
      int4 v = p[s];
      m |= (v.x > 0 ? 1u : 0u) << (s * 4);
      m |= (v.y > 0 ? 1u : 0u) << (s * 4 + 1);
      m |= (v.z > 0 ? 1u : 0u) << (s * 4 + 2);
      m |= (v.w > 0 ? 1u : 0u) << (s * 4 + 3);
    }
    maskRM[w] = m;
  }
}

// ---------------- Kernel 1: h = X@W (fp32), s1 = h@a1, s2 = h@a2, hT = bf16(h)^T ----
__global__ __launch_bounds__(256) void k_h(const float* __restrict__ inp,
                                           const float* __restrict__ Wm,
                                           const float* __restrict__ av,
                                           ushort_t* __restrict__ hT,
                                           float* __restrict__ s1,
                                           float* __restrict__ s2) {
  __shared__ float in_lds[16][FIN];
  __shared__ float h_tile[16][FOUT];
  const int t = threadIdx.x;
  const int r0 = blockIdx.x * 16;

  for (int idx = t; idx < 16 * FIN; idx += 256) {
    int ii = idx >> 8, kk = idx & 255;
    in_lds[ii][kk] = inp[(size_t)(r0 + ii) * FIN + kk];
  }
  __syncthreads();

  const int c2 = (t & 63) * 2;
  const int rg = t >> 6;
  float acc[4][2] = {};
  for (int k = 0; k < FIN; k += 4) {
    float4 iv[4];
#pragma unroll
    for (int q = 0; q < 4; ++q)
      iv[q] = *reinterpret_cast<const float4*>(&in_lds[rg * 4 + q][k]);
#pragma unroll
    for (int kk = 0; kk < 4; ++kk) {
      float2 wp = *reinterpret_cast<const float2*>(&Wm[(size_t)(k + kk) * FOUT + c2]);
#pragma unroll
      for (int q = 0; q < 4; ++q) {
        float x = reinterpret_cast<const float*>(&iv[q])[kk];
        acc[q][0] = fmaf(x, wp.x, acc[q][0]);
        acc[q][1] = fmaf(x, wp.y, acc[q][1]);
      }
    }
  }
#pragma unroll
  for (int q = 0; q < 4; ++q) {
    h_tile[rg * 4 + q][c2] = acc[q][0];
    h_tile[rg * 4 + q][c2 + 1] = acc[q][1];
  }
  __syncthreads();

  const int wv_ = t >> 6, lane = t & 63;
#pragma unroll
  for (int rr = 0; rr < 4; ++rr) {
    int row = wv_ * 4 + rr;
    float h0 = h_tile[row][lane], h1 = h_tile[row][lane + 64];
    float p1 = h0 * av[lane] + h1 * av[lane + 64];
    float p2 = h0 * av[FOUT + lane] + h1 * av[FOUT + lane + 64];
#pragma unroll
    for (int m = 32; m; m >>= 1) {
      p1 += __shfl_xor(p1, m);
      p2 += __shfl_xor(p2, m);
    }
    if (lane == 0) { s1[r0 + row] = p1; s2[r0 + row] = p2; }
  }

  for (int idx = t; idx < 16 * FOUT; idx += 256) {
    int c = idx >> 4, ii = idx & 15;
    hT[(size_t)c * N + r0 + ii] = f2bf(h_tile[ii][c]);
  }
}

// ---------------- Kernel 1b: global max of s2 -------------------------------------
__global__ __launch_bounds__(256) void k_smax(const float* __restrict__ s2,
                                              float* __restrict__ outm) {
  __shared__ float red[4];
  const int t = threadIdx.x;
  float m = -1e30f;
  for (int i = t; i < N; i += 256) m = fmaxf(m, s2[i]);
#pragma unroll
  for (int d = 32; d; d >>= 1) m = fmaxf(m, __shfl_xor(m, d));
  if ((t & 63) == 0) red[t >> 6] = m;
  __syncthreads();
  if (t == 0) outm[0] = fmaxf(fmaxf(red[0], red[1]), fmaxf(red[2], red[3]));
}

// ---------------- Kernel 1c: softmax factor tables --------------------------------
// exp(leakyrelu(x) - mv) = max(exp(x-mv), exp(0.2x-mv)) = max(P_i*Q_j, R_i*S_j).
__global__ __launch_bounds__(256) void k_coef(const float* __restrict__ s1,
                                              const float* __restrict__ s2,
                                              const float* __restrict__ s2max,
                                              float2* __restrict__ QS,
                                              float2* __restrict__ PR) {
  const int i = blockIdx.x * 256 + threadIdx.x;
  const float smx = s2max[0];
  float s1v = s1[i];
  float pre = s1v + smx;
  float mv = pre > 0.f ? pre : ALPHA * pre;  // >= max_j leakyrelu(s1_i+s2_j)
  PR[i] = make_float2(__expf(s1v - mv), __expf(ALPHA * s1v - mv));
  float s2v = s2[i];
  QS[i] = make_float2(__expf(s2v), __expf(ALPHA * s2v));
}

// ---------------- Kernel 2: masked softmax + P@h, 2x B-frag reuse -----------------
// r9 skeleton (16x16 MFMA, swizzled LDS stage, 2 blk/CU) but wave = 32 rows
// (two A-frags afA/afB) x 64-j quarter: each B-fragment ds_read_b128 feeds TWO
// MFMAs -> LDS reads per tile halved (16 vs 32), the modeled ~41 us bottleneck.
// MFMA count / weights / stage traffic unchanged. Weights exp-free; dacc inline.
__global__ __launch_bounds__(512, 4) void k_attn(const unsigned* __restrict__ maskRM,
                                                 const ushort_t* __restrict__ hT,
                                                 const float2* __restrict__ QS,
                                                 const float2* __restrict__ PR,
                                                 float* __restrict__ slab,
                                                 float* __restrict__ denp,
                                                 int jc, int ntiles) {
  __shared__ __align__(16) ushort_t Bt[32768];  // 64 KB staged hT tile
  __shared__ float Dred[8][32];

  const int t = threadIdx.x;
  const int lane = t & 63;
  const int wid = t >> 6;
  const int rb = blockIdx.x & 127;
  const int chunk = blockIdx.x >> 7;
  const int i0 = rb * 64;
  const int jc0 = chunk * jc;

  const int g = wid & 1;        // row-half: rows g*32 .. +32 (two 16-row A-frags)
  const int hf = wid >> 1;      // j-quarter (64 j) of the 256-tile
  const int arow = lane & 15;   // A-frag row / B-frag col
  const int kb = lane >> 4;     // k-slot 0..3
  const int irowA = i0 + g * 32 + arow;
  const int irowB = irowA + 16;

  const float2 prA = PR[irowA], prB = PR[irowB];
  const float PvA = prA.x, RvA = prA.y, PvB = prB.x, RvB = prB.y;

  const unsigned* __restrict__ maskpA =
      maskRM + (size_t)irowA * (N / 32) + (jc0 >> 5) + hf * 2;
  const unsigned* __restrict__ maskpB =
      maskRM + (size_t)irowB * (N / 32) + (jc0 >> 5) + hf * 2;
  const float2* __restrict__ qsp = QS + jc0 + hf * 64 + kb * 8;
  const char* __restrict__ hTb = (const char*)hT;

  f32x4 accA[8], accB[8];
#pragma unroll
  for (int ct = 0; ct < 8; ++ct) {
    accA[ct] = (f32x4){0.f, 0.f, 0.f, 0.f};
    accB[ct] = (f32x4){0.f, 0.f, 0.f, 0.f};
  }
  float daccA = 0.f, daccB = 0.f;

  for (int jt = 0; jt < ntiles; ++jt) {
    const int j0 = jt * 256;

    // ---- stage hT[0:128][jc0+j0:+256] -> Bt (r9-proven swizzle) ----
#pragma unroll
    for (int s = 0; s < 8; ++s) {
      int L = s * 512 + t;          // 16B-granule index
      int rr = L >> 5;              // channel row 0..127
      int boff = (L & 31) * 16;     // byte offset in 512B row
      const char* src =
          hTb + ((size_t)rr * N + jc0 + j0) * 2 + (boff ^ ((rr & 7) << 4));
      GLOAD16(src, (char*)Bt + L * 16);
    }

    // ---- mask words for this wave's 64-j quarter, both row-groups ----
    int2 mwA = *reinterpret_cast<const int2*>(maskpA + jt * 8);
    int2 mwB = *reinterpret_cast<const int2*>(maskpB + jt * 8);

    __syncthreads();  // Bt staged

#pragma unroll
    for (int kq = 0; kq < 2; ++kq) {  // two 32-j K-steps per quarter
      const unsigned wordA = kq ? (unsigned)mwA.y : (unsigned)mwA.x;
      const unsigned wordB = kq ? (unsigned)mwB.y : (unsigned)mwB.x;
      const unsigned w8a = (wordA >> (kb * 8)) & 0xffu;
      const unsigned w8b = (wordB >> (kb * 8)) & 0xffu;
      const float4* q4 = reinterpret_cast<const float4*>(qsp + j0 + kq * 32);

      short8 afA, afB;
      {  // first 4 elems (2 float4 = 4 Q/S pairs live)
        float4 qa = q4[0], qb = q4[1];
        float w;
        w = fmaxf(PvA * qa.x, RvA * qa.y); w = (w8a & 1u) ? w : 0.f; daccA += w; afA[0] = (short)f2bf(w);
        w = fmaxf(PvA * qa.z, RvA * qa.w); w = (w8a & 2u) ? w : 0.f; daccA += w; afA[1] = (short)f2bf(w);
        w = fmaxf(PvA * qb.x, RvA * qb.y); w = (w8a & 4u) ? w : 0.f; daccA += w; afA[2] = (short)f2bf(w);
        w = fmaxf(PvA * qb.z, RvA * qb.w); w = (w8a & 8u) ? w : 0.f; daccA += w; afA[3] = (short)f2bf(w);
        w = fmaxf(PvB * qa.x, RvB * qa.y); w = (w8b & 1u) ? w : 0.f; daccB += w; afB[0] = (short)f2bf(w);
        w = fmaxf(PvB * qa.z, RvB * qa.w); w = (w8b & 2u) ? w : 0.f; daccB += w; afB[1] = (short)f2bf(w);
        w = fmaxf(PvB * qb.x, RvB * qb.y); w = (w8b & 4u) ? w : 0.f; daccB += w; afB[2] = (short)f2bf(w);
        w = fmaxf(PvB * qb.z, RvB * qb.w); w = (w8b & 8u) ? w : 0.f; daccB += w; afB[3] = (short)f2bf(w);
      }
      {  // last 4 elems
        float4 qc = q4[2], qd = q4[3];
        float w;
        w = fmaxf(PvA * qc.x, RvA * qc.y); w = (w8a & 16u) ? w : 0.f; daccA += w; afA[4] = (short)f2bf(w);
        w = fmaxf(PvA * qc.z, RvA * qc.w); w = (w8a & 32u) ? w : 0.f; daccA += w; afA[5] = (short)f2bf(w);
        w = fmaxf(PvA * qd.x, RvA * qd.y); w = (w8a & 64u) ? w : 0.f; daccA += w; afA[6] = (short)f2bf(w);
        w = fmaxf(PvA * qd.z, RvA * qd.w); w = (w8a & 128u) ? w : 0.f; daccA += w; afA[7] = (short)f2bf(w);
        w = fmaxf(PvB * qc.x, RvB * qc.y); w = (w8b & 16u) ? w : 0.f; daccB += w; afB[4] = (short)f2bf(w);
        w = fmaxf(PvB * qc.z, RvB * qc.w); w = (w8b & 32u) ? w : 0.f; daccB += w; afB[5] = (short)f2bf(w);
        w = fmaxf(PvB * qd.x, RvB * qd.y); w = (w8b & 64u) ? w : 0.f; daccB += w; afB[6] = (short)f2bf(w);
        w = fmaxf(PvB * qd.z, RvB * qd.w); w = (w8b & 128u) ? w : 0.f; daccB += w; afB[7] = (short)f2bf(w);
      }

      const int byte0 = hf * 128 + kq * 64 + kb * 16;
#pragma unroll
      for (int cth = 0; cth < 2; ++cth) {  // ct halves: 4 bf live at a time
        short8 bf[4];
#pragma unroll
        for (int c4 = 0; c4 < 4; ++c4) {
          int row = (cth * 4 + c4) * 16 + arow;
          bf[c4] = *reinterpret_cast<const short8*>(
              (const char*)Bt + row * 512 + (byte0 ^ ((row & 7) << 4)));
        }
#pragma unroll
        for (int c4 = 0; c4 < 4; ++c4) {
          accA[cth * 4 + c4] =
              __builtin_amdgcn_mfma_f32_16x16x32_bf16(afA, bf[c4], accA[cth * 4 + c4], 0, 0, 0);
          accB[cth * 4 + c4] =
              __builtin_amdgcn_mfma_f32_16x16x32_bf16(afB, bf[c4], accB[cth * 4 + c4], 0, 0, 0);
        }
      }
    }

    __syncthreads();  // all waves done reading Bt before next stage
  }

  // ---- denominator partials: lanes {r, r+16, r+32, r+48} share a row ----
  daccA += __shfl_xor(daccA, 16);
  daccA += __shfl_xor(daccA, 32);
  daccB += __shfl_xor(daccB, 16);
  daccB += __shfl_xor(daccB, 32);
  if (lane < 16) {
    Dred[wid][lane] = daccA;
    Dred[wid][16 + lane] = daccB;
  }

  // ---- cross-wave (hf) reduction of k-partials in LDS (reuse Bt) ----
  float (*Hred)[132] = (float(*)[132])(void*)Bt;  // 64 x 132 x 4B
  // C/D layout (m89-verified): col = ct*16 + arow, row-in-group = kb*4 + r
  for (int wv = 0; wv < 4; ++wv) {
    if (hf == wv) {
#pragma unroll
      for (int ct = 0; ct < 8; ++ct)
#pragma unroll
        for (int r = 0; r < 4; ++r) {
          int rowA = g * 32 + kb * 4 + r;
          int col = ct * 16 + arow;
          if (wv == 0) {
            Hred[rowA][col] = accA[ct][r];
            Hred[rowA + 16][col] = accB[ct][r];
          } else {
            Hred[rowA][col] += accA[ct][r];
            Hred[rowA + 16][col] += accB[ct][r];
          }
        }
    }
    __syncthreads();
  }

  if (t < 64) {
    int gg = t >> 5, o = t & 31;
    denp[(size_t)chunk * N + i0 + t] =
        Dred[gg][o] + Dred[gg + 2][o] + Dred[gg + 4][o] + Dred[gg + 6][o];
  }

  for (int idx = t; idx < 64 * 128; idx += 512) {
    int r = idx >> 7, c = idx & 127;
    slab[((size_t)chunk * N + i0 + r) * 128 + c] = Hred[r][c];
  }
}

// ---------------- Kernel 3: combine chunks, divide, ELU ---------------------------
__global__ __launch_bounds__(256) void k_fin(const float* __restrict__ slab,
                                             const float* __restrict__ denp,
                                             float* __restrict__ out, int nchunks) {
  const int idx = blockIdx.x * 256 + threadIdx.x;  // < N*FOUT
  const int i = idx >> 7;
  float den = 0.f, v = 0.f;
  for (int k = 0; k < nchunks; ++k) {
    den += denp[(size_t)k * N + i];
    v += slab[(size_t)k * N * FOUT + idx];
  }
  v /= den;
  out[idx] = v > 0.f ? v : (__expf(v) - 1.f);
}

extern "C" void kernel_launch(void* const* d_in, const int* in_sizes, int n_in,
                              void* d_out, int out_size, void* d_ws, size_t ws_size,
                              hipStream_t stream) {
  const float* inp = (const float*)d_in[0];   // [N][FIN] fp32
  const int* adj   = (const int*)d_in[1];     // [N][N] int32
  const float* Wm  = (const float*)d_in[2];   // [FIN][FOUT] fp32
  const float* av  = (const float*)d_in[3];   // [2*FOUT] fp32
  float* out = (float*)d_out;

  // workspace carve-up
  char* ws = (char*)d_ws;
  ushort_t* hT = (ushort_t*)ws;                               // 2 MB
  float* s1    = (float*)(ws + (size_t)FOUT * N * 2);         // 32 KB
  float* s2    = s1 + N;                                      // 32 KB
  float* s2mx  = s2 + N;                                      // 16 B
  float2* QS   = (float2*)(s2mx + 4);                         // 64 KB
  float2* PR   = QS + N;                                      // 64 KB
  unsigned* maskRM = (unsigned*)(PR + N);                     // 8 MB
  float* slab  = (float*)(maskRM + (size_t)N * N / 32);

  const size_t base = (size_t)FOUT * N * 2 + (size_t)N * 4 * 2 + 16 +
                      (size_t)N * 16 + (size_t)N * N / 8;
  int nchunks = 4;  // 512 blocks = 2 blk/CU (proven overlap)
  while (nchunks > 1) {
    size_t need = base + (size_t)nchunks * ((size_t)N * FOUT * 4 + N * 4);
    if (need <= ws_size) break;
    nchunks >>= 1;
  }
  float* denp = slab + (size_t)nchunks * N * FOUT;
  const int jc = N / nchunks;
  const int ntiles = jc / 256;

  k_h<<<N / 16, 256, 0, stream>>>(inp, Wm, av, hT, s1, s2);
  k_smax<<<1, 256, 0, stream>>>(s2, s2mx);
  k_coef<<<N / 256, 256, 0, stream>>>(s1, s2, s2mx, QS, PR);
  k_pack<<<2048, 256, 0, stream>>>(adj, maskRM);
  k_attn<<<128 * nchunks, 512, 0, stream>>>(maskRM, hT, QS, PR, slab, denp, jc, ntiles);
  k_fin<<<(N * FOUT) / 256, 256, 0, stream>>>(slab, denp, out, nchunks);
}

// Round 12
// 198.129 us; speedup vs baseline: 1.1812x; 1.1812x over previous
//
#include <hip/hip_runtime.h>
#include <hip/hip_bf16.h>

#define N 8192
#define FIN 256
#define FOUT 128
#define ALPHA 0.2f

typedef unsigned short ushort_t;
typedef __attribute__((ext_vector_type(8))) short short8;
typedef __attribute__((ext_vector_type(4))) float f32x4;

#define GLOAD16(gp, lp)                                        \
  __builtin_amdgcn_global_load_lds(                            \
      (const __attribute__((address_space(1))) void*)(gp),     \
      (__attribute__((address_space(3))) void*)(lp), 16, 0, 0)

__device__ __forceinline__ ushort_t f2bf(float x) {
  __hip_bfloat16 b = __float2bfloat16(x);  // RNE
  return *reinterpret_cast<ushort_t*>(&b);
}

// ---------------- Kernel 1: h = X@W (fp32), s1 = h@a1, s2 = h@a2, hT = bf16(h)^T ----
__global__ __launch_bounds__(256) void k_h(const float* __restrict__ inp,
                                           const float* __restrict__ Wm,
                                           const float* __restrict__ av,
                                           ushort_t* __restrict__ hT,
                                           float* __restrict__ s1,
                                           float* __restrict__ s2) {
  __shared__ float in_lds[16][FIN];
  __shared__ float h_tile[16][FOUT];
  const int t = threadIdx.x;
  const int r0 = blockIdx.x * 16;

  for (int idx = t; idx < 16 * FIN; idx += 256) {
    int ii = idx >> 8, kk = idx & 255;
    in_lds[ii][kk] = inp[(size_t)(r0 + ii) * FIN + kk];
  }
  __syncthreads();

  const int c2 = (t & 63) * 2;
  const int rg = t >> 6;
  float acc[4][2] = {};
  for (int k = 0; k < FIN; k += 4) {
    float4 iv[4];
#pragma unroll
    for (int q = 0; q < 4; ++q)
      iv[q] = *reinterpret_cast<const float4*>(&in_lds[rg * 4 + q][k]);
#pragma unroll
    for (int kk = 0; kk < 4; ++kk) {
      float2 wp = *reinterpret_cast<const float2*>(&Wm[(size_t)(k + kk) * FOUT + c2]);
#pragma unroll
      for (int q = 0; q < 4; ++q) {
        float x = reinterpret_cast<const float*>(&iv[q])[kk];
        acc[q][0] = fmaf(x, wp.x, acc[q][0]);
        acc[q][1] = fmaf(x, wp.y, acc[q][1]);
      }
    }
  }
#pragma unroll
  for (int q = 0; q < 4; ++q) {
    h_tile[rg * 4 + q][c2] = acc[q][0];
    h_tile[rg * 4 + q][c2 + 1] = acc[q][1];
  }
  __syncthreads();

  const int wv_ = t >> 6, lane = t & 63;
#pragma unroll
  for (int rr = 0; rr < 4; ++rr) {
    int row = wv_ * 4 + rr;
    float h0 = h_tile[row][lane], h1 = h_tile[row][lane + 64];
    float p1 = h0 * av[lane] + h1 * av[lane + 64];
    float p2 = h0 * av[FOUT + lane] + h1 * av[FOUT + lane + 64];
#pragma unroll
    for (int m = 32; m; m >>= 1) {
      p1 += __shfl_xor(p1, m);
      p2 += __shfl_xor(p2, m);
    }
    if (lane == 0) { s1[r0 + row] = p1; s2[r0 + row] = p2; }
  }

  for (int idx = t; idx < 16 * FOUT; idx += 256) {
    int c = idx >> 4, ii = idx & 15;
    hT[(size_t)c * N + r0 + ii] = f2bf(h_tile[ii][c]);
  }
}

// ---------------- Kernel 1b: global max of s2 -------------------------------------
__global__ __launch_bounds__(256) void k_smax(const float* __restrict__ s2,
                                              float* __restrict__ outm) {
  __shared__ float red[4];
  const int t = threadIdx.x;
  float m = -1e30f;
  for (int i = t; i < N; i += 256) m = fmaxf(m, s2[i]);
#pragma unroll
  for (int d = 32; d; d >>= 1) m = fmaxf(m, __shfl_xor(m, d));
  if ((t & 63) == 0) red[t >> 6] = m;
  __syncthreads();
  if (t == 0) outm[0] = fmaxf(fmaxf(red[0], red[1]), fmaxf(red[2], red[3]));
}

// ---------------- Kernel 2: adj bitpack (+ coef tables in first 32 blocks) --------
// Contiguous grid-stride sweep (proven ~5.6 TB/s). Blocks 0..31 first compute the
// softmax factor tables: exp(leakyrelu(s1_i+s2_j)-mv_i) = max(P_i*Q_j, R_i*S_j);
// that 1 us of VALU hides inside the BW-bound stream.
__global__ __launch_bounds__(256) void k_packc(const int* __restrict__ adj,
                                               const float* __restrict__ s1,
                                               const float* __restrict__ s2,
                                               const float* __restrict__ s2max,
                                               unsigned* __restrict__ maskRM,
                                               float2* __restrict__ QS,
                                               float2* __restrict__ PR) {
  const int t = threadIdx.x;
  if (blockIdx.x < 32) {
    const int i = blockIdx.x * 256 + t;
    const float smx = s2max[0];
    float s1v = s1[i];
    float pre = s1v + smx;
    float mv = pre > 0.f ? pre : ALPHA * pre;  // >= max_j leakyrelu(s1_i+s2_j)
    PR[i] = make_float2(__expf(s1v - mv), __expf(ALPHA * s1v - mv));
    float s2v = s2[i];
    QS[i] = make_float2(__expf(s2v), __expf(ALPHA * s2v));
  }
  const size_t tid = (size_t)blockIdx.x * 256 + t;
  const size_t nthr = (size_t)gridDim.x * 256;
  const size_t nwords = (size_t)N * (N / 32);
  for (size_t w = tid; w < nwords; w += nthr) {
    const int4* p = reinterpret_cast<const int4*>(adj + w * 32);
    unsigned m = 0;
#pragma unroll
    for (int s = 0; s < 8; ++s) {
      int4 v = p[s];
      m |= (v.x > 0 ? 1u : 0u) << (s * 4);
      m |= (v.y > 0 ? 1u : 0u) << (s * 4 + 1);
      m |= (v.z > 0 ? 1u : 0u) << (s * 4 + 2);
      m |= (v.w > 0 ? 1u : 0u) << (s * 4 + 3);
    }
    maskRM[w] = m;
  }
}

// ---------------- Kernel 3: masked softmax + P@h (r8 kernel, 2 blk/CU) ------------
// r5/r8 proven skeleton: per 256-j tile, hT slice staged once into swizzled LDS via
// global_load_lds and shared by 8 waves (wave = row-group g x j-half hf); weights
// exp-free max(Pv*Q, Rv*S) gated by L2-resident bitmask; dacc inline.
__global__ __launch_bounds__(512, 4) void k_attn(const unsigned* __restrict__ maskRM,
                                                 const ushort_t* __restrict__ hT,
                                                 const float2* __restrict__ QS,
                                                 const float2* __restrict__ PR,
                                                 float* __restrict__ slab,
                                                 float* __restrict__ denp,
                                                 int jc, int ntiles) {
  __shared__ __align__(16) ushort_t Bt[32768];  // 64 KB staged hT tile
  __shared__ float Dred[8][16];

  const int t = threadIdx.x;
  const int lane = t & 63;
  const int wid = t >> 6;
  const int rb = blockIdx.x & 127;
  const int chunk = blockIdx.x >> 7;
  const int i0 = rb * 64;
  const int jc0 = chunk * jc;

  const int g = wid & 3;        // row-group
  const int hf = wid >> 2;      // j-half of tile
  const int arow = lane & 15;   // A-frag row / B-frag col
  const int kb = lane >> 4;     // k-slot 0..3
  const int irow = i0 + g * 16 + arow;

  const float2 pr = PR[irow];
  const float Pv = pr.x, Rv = pr.y;

  const unsigned* __restrict__ maskp =
      maskRM + (size_t)irow * (N / 32) + ((jc0 + hf * 128) >> 5);
  const float2* __restrict__ qsp = QS + jc0 + hf * 128 + kb * 8;
  const char* __restrict__ hTb = (const char*)hT;

  f32x4 acc[8];
#pragma unroll
  for (int ct = 0; ct < 8; ++ct) acc[ct] = (f32x4){0.f, 0.f, 0.f, 0.f};
  float dacc = 0.f;

  for (int jt = 0; jt < ntiles; ++jt) {
    const int j0 = jt * 256;

    // ---- stage hT[0:128][jc0+j0 : +256] -> Bt, linear dest + swizzled source ----
#pragma unroll
    for (int s = 0; s < 8; ++s) {
      int L = s * 512 + t;          // 16B-granule index
      int rr = L >> 5;              // ct row 0..127
      int boff = (L & 31) * 16;     // byte offset in 512B row
      const char* src =
          hTb + ((size_t)rr * N + jc0 + j0) * 2 + (boff ^ ((rr & 7) << 4));
      GLOAD16(src, (char*)Bt + L * 16);
    }

    // ---- mask words for this tile (4 words = kq 0..3 of this hf-half) ----
    int4 mw = *reinterpret_cast<const int4*>(maskp + (j0 >> 5));

    __syncthreads();  // Bt staged

#pragma unroll
    for (int kq = 0; kq < 4; ++kq) {
      // B-fragments from LDS (swizzled read)
      short8 bf[8];
      const int byte0 = hf * 256 + kq * 64 + kb * 16;
#pragma unroll
      for (int ct = 0; ct < 8; ++ct) {
        int row = ct * 16 + arow;
        int off = row * 512 + (byte0 ^ ((row & 7) << 4));
        bf[ct] = *reinterpret_cast<const short8*>((const char*)Bt + off);
      }
      // weights: w = mask ? max(Pv*Q_j, Rv*S_j) : 0   (no exp)
      const unsigned word = (kq == 0) ? mw.x : (kq == 1) ? mw.y : (kq == 2) ? mw.z : mw.w;
      const unsigned w8 = (word >> (kb * 8)) & 0xffu;
      const float4* q4 = reinterpret_cast<const float4*>(qsp + j0 + kq * 32);
      float4 qa = q4[0], qb = q4[1], qc = q4[2], qd = q4[3];
      short8 af;
      float w;
      w = fmaxf(Pv * qa.x, Rv * qa.y); w = (w8 & 1u) ? w : 0.f; dacc += w; af[0] = (short)f2bf(w);
      w = fmaxf(Pv * qa.z, Rv * qa.w); w = (w8 & 2u) ? w : 0.f; dacc += w; af[1] = (short)f2bf(w);
      w = fmaxf(Pv * qb.x, Rv * qb.y); w = (w8 & 4u) ? w : 0.f; dacc += w; af[2] = (short)f2bf(w);
      w = fmaxf(Pv * qb.z, Rv * qb.w); w = (w8 & 8u) ? w : 0.f; dacc += w; af[3] = (short)f2bf(w);
      w = fmaxf(Pv * qc.x, Rv * qc.y); w = (w8 & 16u) ? w : 0.f; dacc += w; af[4] = (short)f2bf(w);
      w = fmaxf(Pv * qc.z, Rv * qc.w); w = (w8 & 32u) ? w : 0.f; dacc += w; af[5] = (short)f2bf(w);
      w = fmaxf(Pv * qd.x, Rv * qd.y); w = (w8 & 64u) ? w : 0.f; dacc += w; af[6] = (short)f2bf(w);
      w = fmaxf(Pv * qd.z, Rv * qd.w); w = (w8 & 128u) ? w : 0.f; dacc += w; af[7] = (short)f2bf(w);

#pragma unroll
      for (int ct = 0; ct < 8; ++ct)
        acc[ct] = __builtin_amdgcn_mfma_f32_16x16x32_bf16(af, bf[ct], acc[ct], 0, 0, 0);
    }

    __syncthreads();  // all waves done reading Bt before next stage
  }

  // ---- denominator partials: lanes {r, r+16, r+32, r+48} share row r ----
  dacc += __shfl_xor(dacc, 16);
  dacc += __shfl_xor(dacc, 32);
  if (lane < 16) Dred[wid][lane] = dacc;

  // ---- combine the two hf-halves' k-partials in LDS (reuse Bt) ----
  float (*Hred)[132] = (float(*)[132])(void*)Bt;  // 64 x 132 x 4B
  // C/D layout (m89-verified): col = ct*16 + arow, row-in-group = kb*4 + r
  if (hf == 0) {
#pragma unroll
    for (int ct = 0; ct < 8; ++ct)
#pragma unroll
      for (int r = 0; r < 4; ++r)
        Hred[g * 16 + kb * 4 + r][ct * 16 + arow] = acc[ct][r];
  }
  __syncthreads();
  if (hf == 1) {
#pragma unroll
    for (int ct = 0; ct < 8; ++ct)
#pragma unroll
      for (int r = 0; r < 4; ++r)
        Hred[g * 16 + kb * 4 + r][ct * 16 + arow] += acc[ct][r];
  }
  __syncthreads();

  if (t < 64)
    denp[(size_t)chunk * N + i0 + t] = Dred[t >> 4][t & 15] + Dred[(t >> 4) + 4][t & 15];

  for (int idx = t; idx < 64 * 128; idx += 512) {
    int r = idx >> 7, c = idx & 127;
    slab[((size_t)chunk * N + i0 + r) * 128 + c] = Hred[r][c];
  }
}

// ---------------- Kernel 4: combine chunks, divide, ELU ---------------------------
__global__ __launch_bounds__(256) void k_fin(const float* __restrict__ slab,
                                             const float* __restrict__ denp,
                                             float* __restrict__ out, int nchunks) {
  const int idx = blockIdx.x * 256 + threadIdx.x;  // < N*FOUT
  const int i = idx >> 7;
  float den = 0.f, v = 0.f;
  for (int k = 0; k < nchunks; ++k) {
    den += denp[(size_t)k * N + i];
    v += slab[(size_t)k * N * FOUT + idx];
  }
  v /= den;
  out[idx] = v > 0.f ? v : (__expf(v) - 1.f);
}

extern "C" void kernel_launch(void* const* d_in, const int* in_sizes, int n_in,
                              void* d_out, int out_size, void* d_ws, size_t ws_size,
                              hipStream_t stream) {
  const float* inp = (const float*)d_in[0];   // [N][FIN] fp32
  const int* adj   = (const int*)d_in[1];     // [N][N] int32
  const float* Wm  = (const float*)d_in[2];   // [FIN][FOUT] fp32
  const float* av  = (const float*)d_in[3];   // [2*FOUT] fp32
  float* out = (float*)d_out;

  // workspace carve-up
  char* ws = (char*)d_ws;
  ushort_t* hT = (ushort_t*)ws;                               // 2 MB
  float* s1    = (float*)(ws + (size_t)FOUT * N * 2);         // 32 KB
  float* s2    = s1 + N;                                      // 32 KB
  float* s2mx  = s2 + N;                                      // 16 B
  float2* QS   = (float2*)(s2mx + 4);                         // 64 KB
  float2* PR   = QS + N;                                      // 64 KB
  unsigned* maskRM = (unsigned*)(PR + N);                     // 8 MB
  float* slab  = (float*)(maskRM + (size_t)N * N / 32);

  const size_t base = (size_t)FOUT * N * 2 + (size_t)N * 4 * 2 + 16 +
                      (size_t)N * 16 + (size_t)N * N / 8;
  int nchunks = 4;  // 512 blocks = 2 blk/CU (proven overlap)
  while (nchunks > 1) {
    size_t need = base + (size_t)nchunks * ((size_t)N * FOUT * 4 + N * 4);
    if (need <= ws_size) break;
    nchunks >>= 1;
  }
  float* denp = slab + (size_t)nchunks * N * FOUT;
  const int jc = N / nchunks;
  const int ntiles = jc / 256;

  k_h<<<N / 16, 256, 0, stream>>>(inp, Wm, av, hT, s1, s2);
  k_smax<<<1, 256, 0, stream>>>(s2, s2mx);
  k_packc<<<2048, 256, 0, stream>>>(adj, s1, s2, s2mx, maskRM, QS, PR);
  k_attn<<<128 * nchunks, 512, 0, stream>>>(maskRM, hT, QS, PR, slab, denp, jc, ntiles);
  k_fin<<<(N * FOUT) / 256, 256, 0, stream>>>(slab, denp, out, nchunks);
}